// Round 2
// baseline (56.116 us; speedup 1.0000x reference)
//
#include <hip/hip_runtime.h>

#define DD 256
#define SS 128
#define BB 16

// ws layout (floats):
//  LT   [B][D][S]       524288
//  RT   [B][D][S]       524288
//  sumLp[B][8][D]        32768
//  sumRp[B][8][D]        32768
//  absP [B][4][8][64]    32768

// ---------------- projection: L = e@Wl^T + bl, R = e@Wr^T + br ----------------
// grid 512 = 128 token-chunks x 4 d-chunks; 128 threads; tile 16tok x 64d.
__global__ __launch_bounds__(128) void k_proj(
    const int* __restrict__ X, const float* __restrict__ emb,
    const float* __restrict__ Wl, const float* __restrict__ bl,
    const float* __restrict__ Wr, const float* __restrict__ br,
    float* __restrict__ LT, float* __restrict__ RT,
    float* __restrict__ sumLp, float* __restrict__ sumRp)
{
    __shared__ __align__(16) float e_lds[16 * 68];
    __shared__ __align__(16) float wl_lds[64 * 68];
    __shared__ __align__(16) float wr_lds[64 * 68];
    __shared__ float redl[8 * 64];
    __shared__ float redr[8 * 64];
    __shared__ int toks[16];

    const int tid = threadIdx.x;
    const int bx  = blockIdx.x;
    const int tc  = bx >> 2;        // 0..127 token chunk
    const int dc  = bx & 3;         // 0..3   d chunk (64 wide)
    const int b   = tc >> 3;
    const int s0  = (tc & 7) * 16;

    if (tid < 16) toks[tid] = X[b * SS + s0 + tid];

    const int td = tid >> 3;        // 0..15 -> d group of 4
    const int tt = tid & 7;         // 0..7  -> token pair

    float accl[2][4], accr[2][4];
#pragma unroll
    for (int p = 0; p < 2; ++p)
#pragma unroll
        for (int j = 0; j < 4; ++j) { accl[p][j] = 0.f; accr[p][j] = 0.f; }

    __syncthreads();

    for (int k0 = 0; k0 < DD; k0 += 64) {
        // stage e tile [16 tok][64 k]
#pragma unroll
        for (int it = 0; it < 2; ++it) {
            int v = it * 128 + tid;
            int row = v >> 4, c4 = v & 15;
            *(float4*)&e_lds[row * 68 + c4 * 4] =
                *(const float4*)&emb[(size_t)toks[row] * DD + k0 + c4 * 4];
        }
        // stage W tiles [64 d][64 k], rows bank-remapped: lrow=(row&3)*16+(row>>2)
#pragma unroll
        for (int it = 0; it < 8; ++it) {
            int v = it * 128 + tid;
            int row = v >> 4, c4 = v & 15;
            int lrow = (row & 3) * 16 + (row >> 2);
            *(float4*)&wl_lds[lrow * 68 + c4 * 4] =
                *(const float4*)&Wl[(size_t)(dc * 64 + row) * DD + k0 + c4 * 4];
            *(float4*)&wr_lds[lrow * 68 + c4 * 4] =
                *(const float4*)&Wr[(size_t)(dc * 64 + row) * DD + k0 + c4 * 4];
        }
        __syncthreads();

#pragma unroll
        for (int kk = 0; kk < 64; kk += 4) {
            float4 e0 = *(float4*)&e_lds[(tt * 2 + 0) * 68 + kk];
            float4 e1 = *(float4*)&e_lds[(tt * 2 + 1) * 68 + kk];
#pragma unroll
            for (int r = 0; r < 4; ++r) {
                float4 wl = *(float4*)&wl_lds[(r * 16 + td) * 68 + kk];
                float4 wr = *(float4*)&wr_lds[(r * 16 + td) * 68 + kk];
                accl[0][r] = fmaf(e0.x, wl.x, accl[0][r]);
                accl[0][r] = fmaf(e0.y, wl.y, accl[0][r]);
                accl[0][r] = fmaf(e0.z, wl.z, accl[0][r]);
                accl[0][r] = fmaf(e0.w, wl.w, accl[0][r]);
                accl[1][r] = fmaf(e1.x, wl.x, accl[1][r]);
                accl[1][r] = fmaf(e1.y, wl.y, accl[1][r]);
                accl[1][r] = fmaf(e1.z, wl.z, accl[1][r]);
                accl[1][r] = fmaf(e1.w, wl.w, accl[1][r]);
                accr[0][r] = fmaf(e0.x, wr.x, accr[0][r]);
                accr[0][r] = fmaf(e0.y, wr.y, accr[0][r]);
                accr[0][r] = fmaf(e0.z, wr.z, accr[0][r]);
                accr[0][r] = fmaf(e0.w, wr.w, accr[0][r]);
                accr[1][r] = fmaf(e1.x, wr.x, accr[1][r]);
                accr[1][r] = fmaf(e1.y, wr.y, accr[1][r]);
                accr[1][r] = fmaf(e1.z, wr.z, accr[1][r]);
                accr[1][r] = fmaf(e1.w, wr.w, accr[1][r]);
            }
        }
        __syncthreads();
    }

    // bias
    float4 bl4 = *(const float4*)&bl[dc * 64 + td * 4];
    float4 br4 = *(const float4*)&br[dc * 64 + td * 4];
    const float blv[4] = { bl4.x, bl4.y, bl4.z, bl4.w };
    const float brv[4] = { br4.x, br4.y, br4.z, br4.w };
#pragma unroll
    for (int p = 0; p < 2; ++p)
#pragma unroll
        for (int j = 0; j < 4; ++j) { accl[p][j] += blv[j]; accr[p][j] += brv[j]; }

    // transposed stores LT[b][d][s]: lanes tt adjacent -> contiguous s
#pragma unroll
    for (int j = 0; j < 4; ++j) {
        int d = dc * 64 + td * 4 + j;
        float2 vl = make_float2(accl[0][j], accl[1][j]);
        float2 vr = make_float2(accr[0][j], accr[1][j]);
        *(float2*)&LT[((size_t)(b * DD + d)) * SS + s0 + tt * 2] = vl;
        *(float2*)&RT[((size_t)(b * DD + d)) * SS + s0 + tt * 2] = vr;
    }

    // per-chunk token sums (for the separable mean term)
    float4 sl4 = make_float4(accl[0][0] + accl[1][0], accl[0][1] + accl[1][1],
                             accl[0][2] + accl[1][2], accl[0][3] + accl[1][3]);
    float4 sr4 = make_float4(accr[0][0] + accr[1][0], accr[0][1] + accr[1][1],
                             accr[0][2] + accr[1][2], accr[0][3] + accr[1][3]);
    *(float4*)&redl[tt * 64 + td * 4] = sl4;
    *(float4*)&redr[tt * 64 + td * 4] = sr4;
    __syncthreads();
    if (tid < 64) {
        float sl = 0.f, sr = 0.f;
#pragma unroll
        for (int t = 0; t < 8; ++t) { sl += redl[t * 64 + tid]; sr += redr[t * 64 + tid]; }
        int sc = tc & 7;
        sumLp[(b * 8 + sc) * DD + dc * 64 + tid] = sl;
        sumRp[(b * 8 + sc) * DD + dc * 64 + tid] = sr;
    }
}

// ---------------- all-pairs |L_i + R_j| partial sums ----------------
// grid 512 = b x 4 dchunk x 8 isplit; 256 threads = 64 d x 4 j-groups
__global__ __launch_bounds__(256) void k_pairs(
    const float* __restrict__ LT, const float* __restrict__ RT,
    float* __restrict__ absP)
{
    __shared__ float Ll[64 * 17];    // [d][i16] stride 17 -> 2-way (free)
    __shared__ float Rl[64 * 129];   // [d][j128] stride 129 -> 2-way
    __shared__ float red[256];
    const int tid = threadIdx.x;
    const int bx  = blockIdx.x;
    const int b   = bx >> 5;
    const int dc  = (bx >> 3) & 3;
    const int is  = bx & 7;

    const float* Lg = LT + ((size_t)(b * DD + dc * 64)) * SS;
    const float* Rg = RT + ((size_t)(b * DD + dc * 64)) * SS;

    // L chunk: 64 rows x 16 cols = 256 float4 (1 per thread)
    {
        int r = tid >> 2, c4 = tid & 3;
        float4 x = *(const float4*)&Lg[r * SS + is * 16 + c4 * 4];
        float* p = &Ll[r * 17 + c4 * 4];
        p[0] = x.x; p[1] = x.y; p[2] = x.z; p[3] = x.w;
    }
    // R chunk: 64 rows x 128 cols = 2048 float4
#pragma unroll
    for (int it = 0; it < 8; ++it) {
        int v = it * 256 + tid;
        int r = v >> 5, c4 = v & 31;
        float4 x = *(const float4*)&Rg[r * SS + c4 * 4];
        float* p = &Rl[r * 129 + c4 * 4];
        p[0] = x.x; p[1] = x.y; p[2] = x.z; p[3] = x.w;
    }
    __syncthreads();

    const int dl = tid & 63;
    const int jg = tid >> 6;
    float rr[32];
#pragma unroll
    for (int j = 0; j < 32; ++j) rr[j] = Rl[dl * 129 + jg * 32 + j];

    float a0 = 0.f, a1 = 0.f, a2 = 0.f, a3 = 0.f;
#pragma unroll
    for (int i = 0; i < 16; ++i) {
        float l = Ll[dl * 17 + i];
#pragma unroll
        for (int j = 0; j < 32; j += 4) {
            a0 += fabsf(l + rr[j + 0]);
            a1 += fabsf(l + rr[j + 1]);
            a2 += fabsf(l + rr[j + 2]);
            a3 += fabsf(l + rr[j + 3]);
        }
    }
    red[tid] = (a0 + a1) + (a2 + a3);
    __syncthreads();
    if (tid < 64) {
        float s = red[tid] + red[tid + 64] + red[tid + 128] + red[tid + 192];
        absP[((b * 4 + dc) * 8 + is) * 64 + tid] = s;
    }
}

// ---------------- final: pooled affine ----------------
__global__ __launch_bounds__(256) void k_final(
    const float* __restrict__ sumLp, const float* __restrict__ sumRp,
    const float* __restrict__ absP,
    const float* __restrict__ Wrel, const float* __restrict__ brel,
    float* __restrict__ out)
{
    __shared__ float plds[DD];
    const int tid = threadIdx.x;
    const int b   = blockIdx.x;

    float sl = 0.f, sr = 0.f;
#pragma unroll
    for (int sc = 0; sc < 8; ++sc) {
        sl += sumLp[(b * 8 + sc) * DD + tid];
        sr += sumRp[(b * 8 + sc) * DD + tid];
    }
    const int dc = tid >> 6, dl = tid & 63;
    float sa = 0.f;
#pragma unroll
    for (int is = 0; is < 8; ++is)
        sa += absP[((b * 4 + dc) * 8 + is) * 64 + dl];

    // pooled = (S*(sumL+sumR) + sumAbs) / (2*S*S)
    plds[tid] = (128.0f * (sl + sr) + sa) * (1.0f / 32768.0f);
    __syncthreads();

    float acc = brel[tid];
    const float4* w4 = (const float4*)(Wrel + (size_t)tid * DD);
#pragma unroll
    for (int k4 = 0; k4 < DD / 4; ++k4) {
        float4 p = *(float4*)&plds[k4 * 4];
        float4 w = w4[k4];
        acc = fmaf(p.x, w.x, acc);
        acc = fmaf(p.y, w.y, acc);
        acc = fmaf(p.z, w.z, acc);
        acc = fmaf(p.w, w.w, acc);
    }
    out[b * DD + tid] = acc;
}

extern "C" void kernel_launch(void* const* d_in, const int* in_sizes, int n_in,
                              void* d_out, int out_size, void* d_ws, size_t ws_size,
                              hipStream_t stream) {
    const int*   X    = (const int*)d_in[0];
    const float* emb  = (const float*)d_in[1];
    const float* Wl   = (const float*)d_in[2];
    const float* bl   = (const float*)d_in[3];
    const float* Wr   = (const float*)d_in[4];
    const float* br   = (const float*)d_in[5];
    const float* Wrel = (const float*)d_in[6];
    const float* brel = (const float*)d_in[7];
    float* out = (float*)d_out;

    float* ws = (float*)d_ws;
    float* LT    = ws;
    float* RT    = LT + (size_t)BB * DD * SS;
    float* sumLp = RT + (size_t)BB * DD * SS;
    float* sumRp = sumLp + BB * 8 * DD;
    float* absP  = sumRp + BB * 8 * DD;

    k_proj<<<512, 128, 0, stream>>>(X, emb, Wl, bl, Wr, br,
                                    LT, RT, sumLp, sumRp);
    k_pairs<<<512, 256, 0, stream>>>(LT, RT, absP);
    k_final<<<BB, 256, 0, stream>>>(sumLp, sumRp, absP, Wrel, brel, out);
}

// Round 3
// 46.725 us; speedup vs baseline: 1.2010x; 1.2010x over previous
//
#include <hip/hip_runtime.h>

#define DD 256
#define SS 128
#define BB 16

// ws layout (floats):
//  LTp [2][B][D][S]   1048576   (K-split partials)
//  RTp [2][B][D][S]   1048576
//  sumLp[B][8][D]       32768   (slot = (tc&3)*2 + ks)
//  sumRp[B][8][D]       32768
//  absP [B][4][8][64]   32768

#define KPART ((size_t)BB * DD * SS)   // 524288 floats per K-partial

// ---------------- projection: [2048 tok x 256 k] @ [256 k x 512 cols(L|R)] ----------------
// grid 512 = 64 token-chunks x 4 col-chunks x 2 k-splits; 256 threads.
// tile: 32 tok x 128 cols x 128 k-half; micro 4 tok x 4 col; k-chunk 32.
__global__ __launch_bounds__(256) void k_proj(
    const int* __restrict__ X, const float* __restrict__ emb,
    const float* __restrict__ Wl, const float* __restrict__ bl,
    const float* __restrict__ Wr, const float* __restrict__ br,
    float* __restrict__ LTp, float* __restrict__ RTp,
    float* __restrict__ sumLp, float* __restrict__ sumRp)
{
    __shared__ __align__(16) float e_lds[32 * 33];
    __shared__ __align__(16) float w_lds[128 * 33];
    __shared__ float red[8 * 128];
    __shared__ int toks[32];

    const int tid = threadIdx.x;
    const int bx  = blockIdx.x;
    const int ks  = bx & 1;
    const int cc  = (bx >> 1) & 3;
    const int tc  = bx >> 3;          // 0..63
    const int b   = tc >> 2;
    const int s0  = (tc & 3) * 32;
    const int kh  = ks * 128;

    const float* Wsrc = (cc < 2) ? Wl : Wr;
    const int    dr0  = (cc & 1) * 128;   // W row base within its matrix

    if (tid < 32) toks[tid] = X[b * SS + s0 + tid];

    const int ty = tid >> 5;          // 0..7  -> 4-token group
    const int tx = tid & 31;          // 0..31 -> 4-col group

    float acc[4][4];
#pragma unroll
    for (int j = 0; j < 4; ++j)
#pragma unroll
        for (int q = 0; q < 4; ++q) acc[j][q] = 0.f;

    // staging register buffers
    float4 re, rw0, rw1, rw2, rw3;
    const int erow = tid >> 3, ec4 = tid & 7;     // e: 1 float4/thread
    __syncthreads();                               // toks visible

    // prefetch chunk 0
    {
        const int k0 = kh;
        re  = *(const float4*)&emb[(size_t)toks[erow] * DD + k0 + ec4 * 4];
        rw0 = *(const float4*)&Wsrc[(size_t)(dr0 + ((0*256+tid) >> 3)) * DD + k0 + ec4 * 4];
        rw1 = *(const float4*)&Wsrc[(size_t)(dr0 + ((1*256+tid) >> 3)) * DD + k0 + ec4 * 4];
        rw2 = *(const float4*)&Wsrc[(size_t)(dr0 + ((2*256+tid) >> 3)) * DD + k0 + ec4 * 4];
        rw3 = *(const float4*)&Wsrc[(size_t)(dr0 + ((3*256+tid) >> 3)) * DD + k0 + ec4 * 4];
    }

    for (int kc = 0; kc < 4; ++kc) {
        __syncthreads();   // previous compute done reading LDS
        *(float4*)&e_lds[erow * 33 + ec4 * 4] = re;
        *(float4*)&w_lds[((0*256+tid) >> 3) * 33 + ec4 * 4] = rw0;
        *(float4*)&w_lds[((1*256+tid) >> 3) * 33 + ec4 * 4] = rw1;
        *(float4*)&w_lds[((2*256+tid) >> 3) * 33 + ec4 * 4] = rw2;
        *(float4*)&w_lds[((3*256+tid) >> 3) * 33 + ec4 * 4] = rw3;
        __syncthreads();   // staging visible

        if (kc < 3) {      // prefetch next chunk (hides under compute)
            const int k0 = kh + (kc + 1) * 32;
            re  = *(const float4*)&emb[(size_t)toks[erow] * DD + k0 + ec4 * 4];
            rw0 = *(const float4*)&Wsrc[(size_t)(dr0 + ((0*256+tid) >> 3)) * DD + k0 + ec4 * 4];
            rw1 = *(const float4*)&Wsrc[(size_t)(dr0 + ((1*256+tid) >> 3)) * DD + k0 + ec4 * 4];
            rw2 = *(const float4*)&Wsrc[(size_t)(dr0 + ((2*256+tid) >> 3)) * DD + k0 + ec4 * 4];
            rw3 = *(const float4*)&Wsrc[(size_t)(dr0 + ((3*256+tid) >> 3)) * DD + k0 + ec4 * 4];
        }

#pragma unroll
        for (int kk = 0; kk < 32; kk += 4) {
            float4 ev0 = *(float4*)&e_lds[(4*ty + 0) * 33 + kk];
            float4 ev1 = *(float4*)&e_lds[(4*ty + 1) * 33 + kk];
            float4 ev2 = *(float4*)&e_lds[(4*ty + 2) * 33 + kk];
            float4 ev3 = *(float4*)&e_lds[(4*ty + 3) * 33 + kk];
            float4 wv0 = *(float4*)&w_lds[(4*tx + 0) * 33 + kk];
            float4 wv1 = *(float4*)&w_lds[(4*tx + 1) * 33 + kk];
            float4 wv2 = *(float4*)&w_lds[(4*tx + 2) * 33 + kk];
            float4 wv3 = *(float4*)&w_lds[(4*tx + 3) * 33 + kk];
            const float4 ev[4] = { ev0, ev1, ev2, ev3 };
            const float4 wv[4] = { wv0, wv1, wv2, wv3 };
#pragma unroll
            for (int j = 0; j < 4; ++j)
#pragma unroll
                for (int q = 0; q < 4; ++q) {
                    acc[j][q] = fmaf(ev[j].x, wv[q].x, acc[j][q]);
                    acc[j][q] = fmaf(ev[j].y, wv[q].y, acc[j][q]);
                    acc[j][q] = fmaf(ev[j].z, wv[q].z, acc[j][q]);
                    acc[j][q] = fmaf(ev[j].w, wv[q].w, acc[j][q]);
                }
        }
    }

    // bias only on k-split 0
    if (ks == 0) {
        const float* bsrc = (cc < 2) ? bl : br;
        float4 b4 = *(const float4*)&bsrc[dr0 + 4 * tx];
        const float bv[4] = { b4.x, b4.y, b4.z, b4.w };
#pragma unroll
        for (int j = 0; j < 4; ++j)
#pragma unroll
            for (int q = 0; q < 4; ++q) acc[j][q] += bv[q];
    }

    // partial stores: [ks][b][d][s], thread covers toks s0+4ty.. (contig 4)
    float* Tbase = ((cc < 2) ? LTp : RTp) + (size_t)ks * KPART;
#pragma unroll
    for (int q = 0; q < 4; ++q) {
        int d = dr0 + 4 * tx + q;
        float4 sv = make_float4(acc[0][q], acc[1][q], acc[2][q], acc[3][q]);
        *(float4*)&Tbase[((size_t)(b * DD + d)) * SS + s0 + 4 * ty] = sv;
    }

    // token-sum partials for the separable mean term
    {
        float4 ts = make_float4(acc[0][0]+acc[1][0]+acc[2][0]+acc[3][0],
                                acc[0][1]+acc[1][1]+acc[2][1]+acc[3][1],
                                acc[0][2]+acc[1][2]+acc[2][2]+acc[3][2],
                                acc[0][3]+acc[1][3]+acc[2][3]+acc[3][3]);
        *(float4*)&red[ty * 128 + 4 * tx] = ts;
    }
    __syncthreads();
    if (tid < 128) {
        float s = 0.f;
#pragma unroll
        for (int t = 0; t < 8; ++t) s += red[t * 128 + tid];
        int slot = (tc & 3) * 2 + ks;
        float* sp = (cc < 2) ? sumLp : sumRp;
        sp[(b * 8 + slot) * DD + dr0 + tid] = s;
    }
}

// ---------------- all-pairs |L_i + R_j| partial sums ----------------
// grid 512 = b x 4 dchunk x 8 isplit; 256 threads = 64 d x 4 j-groups
__global__ __launch_bounds__(256) void k_pairs(
    const float* __restrict__ LTp, const float* __restrict__ RTp,
    float* __restrict__ absP)
{
    __shared__ float Ll[64 * 17];
    __shared__ float Rl[64 * 129];
    __shared__ float red[256];
    const int tid = threadIdx.x;
    const int bx  = blockIdx.x;
    const int b   = bx >> 5;
    const int dc  = (bx >> 3) & 3;
    const int is  = bx & 7;

    const float* Lg = LTp + ((size_t)(b * DD + dc * 64)) * SS;
    const float* Rg = RTp + ((size_t)(b * DD + dc * 64)) * SS;

    // L chunk: 64 rows x 16 cols, sum of two K-partials
    {
        int r = tid >> 2, c4 = tid & 3;
        size_t off = (size_t)r * SS + is * 16 + c4 * 4;
        float4 x0 = *(const float4*)&Lg[off];
        float4 x1 = *(const float4*)&Lg[KPART + off];
        float* p = &Ll[r * 17 + c4 * 4];
        p[0] = x0.x + x1.x; p[1] = x0.y + x1.y;
        p[2] = x0.z + x1.z; p[3] = x0.w + x1.w;
    }
    // R chunk: 64 rows x 128 cols
#pragma unroll
    for (int it = 0; it < 8; ++it) {
        int v = it * 256 + tid;
        int r = v >> 5, c4 = v & 31;
        size_t off = (size_t)r * SS + c4 * 4;
        float4 x0 = *(const float4*)&Rg[off];
        float4 x1 = *(const float4*)&Rg[KPART + off];
        float* p = &Rl[r * 129 + c4 * 4];
        p[0] = x0.x + x1.x; p[1] = x0.y + x1.y;
        p[2] = x0.z + x1.z; p[3] = x0.w + x1.w;
    }
    __syncthreads();

    const int dl = tid & 63;
    const int jg = tid >> 6;
    float rr[32];
#pragma unroll
    for (int j = 0; j < 32; ++j) rr[j] = Rl[dl * 129 + jg * 32 + j];

    float a0 = 0.f, a1 = 0.f, a2 = 0.f, a3 = 0.f;
#pragma unroll
    for (int i = 0; i < 16; ++i) {
        float l = Ll[dl * 17 + i];
#pragma unroll
        for (int j = 0; j < 32; j += 4) {
            a0 += fabsf(l + rr[j + 0]);
            a1 += fabsf(l + rr[j + 1]);
            a2 += fabsf(l + rr[j + 2]);
            a3 += fabsf(l + rr[j + 3]);
        }
    }
    red[tid] = (a0 + a1) + (a2 + a3);
    __syncthreads();
    if (tid < 64) {
        float s = red[tid] + red[tid + 64] + red[tid + 128] + red[tid + 192];
        absP[((b * 4 + dc) * 8 + is) * 64 + tid] = s;
    }
}

// ---------------- final: pooled affine ----------------
__global__ __launch_bounds__(256) void k_final(
    const float* __restrict__ sumLp, const float* __restrict__ sumRp,
    const float* __restrict__ absP,
    const float* __restrict__ Wrel, const float* __restrict__ brel,
    float* __restrict__ out)
{
    __shared__ float plds[DD];
    const int tid = threadIdx.x;
    const int b   = blockIdx.x;

    float sl = 0.f, sr = 0.f;
#pragma unroll
    for (int sc = 0; sc < 8; ++sc) {
        sl += sumLp[(b * 8 + sc) * DD + tid];
        sr += sumRp[(b * 8 + sc) * DD + tid];
    }
    const int dc = tid >> 6, dl = tid & 63;
    float sa = 0.f;
#pragma unroll
    for (int is = 0; is < 8; ++is)
        sa += absP[((b * 4 + dc) * 8 + is) * 64 + dl];

    // pooled = (S*(sumL+sumR) + sumAbs) / (2*S*S)
    plds[tid] = (128.0f * (sl + sr) + sa) * (1.0f / 32768.0f);
    __syncthreads();

    float acc = brel[tid];
    const float4* w4 = (const float4*)(Wrel + (size_t)tid * DD);
#pragma unroll
    for (int k4 = 0; k4 < DD / 4; ++k4) {
        float4 p = *(float4*)&plds[k4 * 4];
        float4 w = w4[k4];
        acc = fmaf(p.x, w.x, acc);
        acc = fmaf(p.y, w.y, acc);
        acc = fmaf(p.z, w.z, acc);
        acc = fmaf(p.w, w.w, acc);
    }
    out[b * DD + tid] = acc;
}

extern "C" void kernel_launch(void* const* d_in, const int* in_sizes, int n_in,
                              void* d_out, int out_size, void* d_ws, size_t ws_size,
                              hipStream_t stream) {
    const int*   X    = (const int*)d_in[0];
    const float* emb  = (const float*)d_in[1];
    const float* Wl   = (const float*)d_in[2];
    const float* bl   = (const float*)d_in[3];
    const float* Wr   = (const float*)d_in[4];
    const float* br   = (const float*)d_in[5];
    const float* Wrel = (const float*)d_in[6];
    const float* brel = (const float*)d_in[7];
    float* out = (float*)d_out;

    float* ws = (float*)d_ws;
    float* LTp   = ws;
    float* RTp   = LTp + 2 * KPART;
    float* sumLp = RTp + 2 * KPART;
    float* sumRp = sumLp + BB * 8 * DD;
    float* absP  = sumRp + BB * 8 * DD;

    k_proj<<<512, 256, 0, stream>>>(X, emb, Wl, bl, Wr, br,
                                    LTp, RTp, sumLp, sumRp);
    k_pairs<<<512, 256, 0, stream>>>(LTp, RTp, absP);
    k_final<<<BB, 256, 0, stream>>>(sumLp, sumRp, absP, Wrel, brel, out);
}

// Round 4
// 34.493 us; speedup vs baseline: 1.6269x; 1.3546x over previous
//
#include <hip/hip_runtime.h>
#include <hip/hip_bf16.h>

#define DD 256
#define SS 128
#define BB 16

typedef __attribute__((ext_vector_type(8))) short bf16x8;
typedef __attribute__((ext_vector_type(4))) float f32x4;

static __device__ __forceinline__ short f2bf(float f) {
    __hip_bfloat16 h = __float2bfloat16(f);
    return *reinterpret_cast<short*>(&h);
}

// swizzled byte offset within a [64 rows][256 bf16 = 512B] LDS tile
static __device__ __forceinline__ int swz_off(int r, int kb) {
    return r * 512 + (kb ^ ((r & 7) << 4) ^ (((r >> 3) & 3) << 7));
}

// ws layout (floats):
//  LT   [B][D][S]    524288
//  RT   [B][D][S]    524288
//  sumLp[B][2][D]      8192
//  sumRp[B][2][D]      8192
//  absP [B][4][8][64] 32768

// ---------------- projection via bf16 MFMA ----------------
// grid 256 = 32 token-chunks(64 tok) x 8 col-chunks(64 of L|R); 256 thr = 4 waves.
__global__ __launch_bounds__(256) void k_proj(
    const int* __restrict__ X, const float* __restrict__ emb,
    const float* __restrict__ Wl, const float* __restrict__ bl,
    const float* __restrict__ Wr, const float* __restrict__ br,
    float* __restrict__ LT, float* __restrict__ RT,
    float* __restrict__ sumLp, float* __restrict__ sumRp)
{
    __shared__ __align__(16) short Ebf[64 * 256];
    __shared__ __align__(16) short Wbf[64 * 256];
    __shared__ __align__(16) float Ot[64 * 68];
    __shared__ float red[4 * 64];
    __shared__ int toks[64];

    const int tid = threadIdx.x;
    const int bx  = blockIdx.x;
    const int tc  = bx >> 3;      // 0..31 : 64-token chunk
    const int cc  = bx & 7;       // 0..7  : 64-col chunk (0-3 -> L, 4-7 -> R)
    const int b   = tc >> 1;
    const int s0  = (tc & 1) * 64;
    const float* Wsrc = (cc < 4) ? Wl : Wr;
    const float* bsrc = (cc < 4) ? bl : br;
    const int dr0 = (cc & 3) * 64;

    if (tid < 64) toks[tid] = X[b * SS + s0 + tid];
    __syncthreads();

    char* Eb = (char*)Ebf;
    char* Wb = (char*)Wbf;
    {
        const int r  = tid & 63;     // row (token / W-col)
        const int wq = tid >> 6;     // 64-float k-window
        const float4* es  = (const float4*)(emb + (size_t)toks[r] * DD + wq * 64);
        const float4* wsp = (const float4*)(Wsrc + (size_t)(dr0 + r) * DD + wq * 64);
        float4 ev[16], wv[16];
#pragma unroll
        for (int i = 0; i < 16; ++i) ev[i] = es[i];
#pragma unroll
        for (int i = 0; i < 16; ++i) wv[i] = wsp[i];
#pragma unroll
        for (int g = 0; g < 8; ++g) {
            bf16x8 pe, pw;
            pe[0] = f2bf(ev[2*g].x);   pe[1] = f2bf(ev[2*g].y);
            pe[2] = f2bf(ev[2*g].z);   pe[3] = f2bf(ev[2*g].w);
            pe[4] = f2bf(ev[2*g+1].x); pe[5] = f2bf(ev[2*g+1].y);
            pe[6] = f2bf(ev[2*g+1].z); pe[7] = f2bf(ev[2*g+1].w);
            pw[0] = f2bf(wv[2*g].x);   pw[1] = f2bf(wv[2*g].y);
            pw[2] = f2bf(wv[2*g].z);   pw[3] = f2bf(wv[2*g].w);
            pw[4] = f2bf(wv[2*g+1].x); pw[5] = f2bf(wv[2*g+1].y);
            pw[6] = f2bf(wv[2*g+1].z); pw[7] = f2bf(wv[2*g+1].w);
            const int off = swz_off(r, wq * 128 + g * 16);
            *(bf16x8*)(Eb + off) = pe;
            *(bf16x8*)(Wb + off) = pw;
        }
    }
    __syncthreads();

    const int w    = tid >> 6;
    const int lane = tid & 63;
    const int wm = w >> 1, wn = w & 1;    // wave's 32x32 quadrant
    const int lr = lane & 15, lk = lane >> 4;

    f32x4 zz = {0.f, 0.f, 0.f, 0.f};
    f32x4 acc00 = zz, acc01 = zz, acc10 = zz, acc11 = zz;

#pragma unroll
    for (int ks = 0; ks < 8; ++ks) {
        const int kb = ks * 64 + lk * 16;
        bf16x8 a0 = *(bf16x8*)(Eb + swz_off(wm * 32 + lr,      kb));
        bf16x8 a1 = *(bf16x8*)(Eb + swz_off(wm * 32 + 16 + lr, kb));
        bf16x8 b0 = *(bf16x8*)(Wb + swz_off(wn * 32 + lr,      kb));
        bf16x8 b1 = *(bf16x8*)(Wb + swz_off(wn * 32 + 16 + lr, kb));
        acc00 = __builtin_amdgcn_mfma_f32_16x16x32_bf16(a0, b0, acc00, 0, 0, 0);
        acc01 = __builtin_amdgcn_mfma_f32_16x16x32_bf16(a0, b1, acc01, 0, 0, 0);
        acc10 = __builtin_amdgcn_mfma_f32_16x16x32_bf16(a1, b0, acc10, 0, 0, 0);
        acc11 = __builtin_amdgcn_mfma_f32_16x16x32_bf16(a1, b1, acc11, 0, 0, 0);
    }

    // bias + transpose via LDS. D mapping: col(n)=lane&15, row(m)=(lane>>4)*4+reg
    {
        const float bv0 = bsrc[dr0 + wn * 32 + lr];
        const float bv1 = bsrc[dr0 + wn * 32 + 16 + lr];
        const int dl0 = wn * 32 + lr;
#pragma unroll
        for (int reg = 0; reg < 4; ++reg) {
            const int sl0 = wm * 32 + lk * 4 + reg;
            Ot[(dl0     ) * 68 + sl0     ] = acc00[reg] + bv0;
            Ot[(dl0 + 16) * 68 + sl0     ] = acc01[reg] + bv1;
            Ot[(dl0     ) * 68 + sl0 + 16] = acc10[reg] + bv0;
            Ot[(dl0 + 16) * 68 + sl0 + 16] = acc11[reg] + bv1;
        }
    }
    __syncthreads();

    // coalesced transposed store: LT[b][d][s]
    float* Tb = (cc < 4) ? LT : RT;
    {
        const int dl = tid >> 2, sq = tid & 3;
        float* dst = Tb + ((size_t)(b * DD + dr0 + dl)) * SS + s0 + sq * 16;
#pragma unroll
        for (int i = 0; i < 4; ++i)
            *(float4*)(dst + i * 4) = *(float4*)&Ot[dl * 68 + sq * 16 + i * 4];
    }
    // per-block token sums (separable mean term), deterministic partials
    {
        const int d = tid & 63, sq = tid >> 6;
        float s = 0.f;
#pragma unroll
        for (int i = 0; i < 4; ++i) {
            float4 v = *(float4*)&Ot[d * 68 + sq * 16 + i * 4];
            s += (v.x + v.y) + (v.z + v.w);
        }
        red[sq * 64 + d] = s;
    }
    __syncthreads();
    if (tid < 64) {
        float s = red[tid] + red[64 + tid] + red[128 + tid] + red[192 + tid];
        float* sp = (cc < 4) ? sumLp : sumRp;
        sp[(b * 2 + (tc & 1)) * DD + dr0 + tid] = s;
    }
}

// ---------------- all-pairs |L_i + R_j| partial sums ----------------
// grid 512 = b x 4 dchunk x 8 isplit; 256 threads = 64 d x 4 j-groups
__global__ __launch_bounds__(256) void k_pairs(
    const float* __restrict__ LT, const float* __restrict__ RT,
    float* __restrict__ absP)
{
    __shared__ float Ll[64 * 17];
    __shared__ float Rl[64 * 129];
    __shared__ float red[256];
    const int tid = threadIdx.x;
    const int bx  = blockIdx.x;
    const int b   = bx >> 5;
    const int dc  = (bx >> 3) & 3;
    const int is  = bx & 7;

    const float* Lg = LT + ((size_t)(b * DD + dc * 64)) * SS;
    const float* Rg = RT + ((size_t)(b * DD + dc * 64)) * SS;

    {
        int r = tid >> 2, c4 = tid & 3;
        float4 x = *(const float4*)&Lg[(size_t)r * SS + is * 16 + c4 * 4];
        float* p = &Ll[r * 17 + c4 * 4];
        p[0] = x.x; p[1] = x.y; p[2] = x.z; p[3] = x.w;
    }
#pragma unroll
    for (int it = 0; it < 8; ++it) {
        int v = it * 256 + tid;
        int r = v >> 5, c4 = v & 31;
        float4 x = *(const float4*)&Rg[(size_t)r * SS + c4 * 4];
        float* p = &Rl[r * 129 + c4 * 4];
        p[0] = x.x; p[1] = x.y; p[2] = x.z; p[3] = x.w;
    }
    __syncthreads();

    const int dl = tid & 63;
    const int jg = tid >> 6;
    float rr[32];
#pragma unroll
    for (int j = 0; j < 32; ++j) rr[j] = Rl[dl * 129 + jg * 32 + j];

    float a0 = 0.f, a1 = 0.f, a2 = 0.f, a3 = 0.f;
#pragma unroll
    for (int i = 0; i < 16; ++i) {
        float l = Ll[dl * 17 + i];
#pragma unroll
        for (int j = 0; j < 32; j += 4) {
            a0 += fabsf(l + rr[j + 0]);
            a1 += fabsf(l + rr[j + 1]);
            a2 += fabsf(l + rr[j + 2]);
            a3 += fabsf(l + rr[j + 3]);
        }
    }
    red[tid] = (a0 + a1) + (a2 + a3);
    __syncthreads();
    if (tid < 64) {
        float s = red[tid] + red[tid + 64] + red[tid + 128] + red[tid + 192];
        absP[((b * 4 + dc) * 8 + is) * 64 + tid] = s;
    }
}

// ---------------- final: pooled affine ----------------
__global__ __launch_bounds__(256) void k_final(
    const float* __restrict__ sumLp, const float* __restrict__ sumRp,
    const float* __restrict__ absP,
    const float* __restrict__ Wrel, const float* __restrict__ brel,
    float* __restrict__ out)
{
    __shared__ float plds[DD];
    const int tid = threadIdx.x;
    const int b   = blockIdx.x;

    float sl = sumLp[(b * 2 + 0) * DD + tid] + sumLp[(b * 2 + 1) * DD + tid];
    float sr = sumRp[(b * 2 + 0) * DD + tid] + sumRp[(b * 2 + 1) * DD + tid];

    const int dc = tid >> 6, dl = tid & 63;
    float sa = 0.f;
#pragma unroll
    for (int is = 0; is < 8; ++is)
        sa += absP[((b * 4 + dc) * 8 + is) * 64 + dl];

    // pooled = (S*(sumL+sumR) + sumAbs) / (2*S*S)
    plds[tid] = (128.0f * (sl + sr) + sa) * (1.0f / 32768.0f);
    __syncthreads();

    float acc = brel[tid];
    const float4* w4 = (const float4*)(Wrel + (size_t)tid * DD);
#pragma unroll
    for (int k4 = 0; k4 < DD / 4; ++k4) {
        float4 p = *(float4*)&plds[k4 * 4];
        float4 w = w4[k4];
        acc = fmaf(p.x, w.x, acc);
        acc = fmaf(p.y, w.y, acc);
        acc = fmaf(p.z, w.z, acc);
        acc = fmaf(p.w, w.w, acc);
    }
    out[b * DD + tid] = acc;
}

extern "C" void kernel_launch(void* const* d_in, const int* in_sizes, int n_in,
                              void* d_out, int out_size, void* d_ws, size_t ws_size,
                              hipStream_t stream) {
    const int*   X    = (const int*)d_in[0];
    const float* emb  = (const float*)d_in[1];
    const float* Wl   = (const float*)d_in[2];
    const float* bl   = (const float*)d_in[3];
    const float* Wr   = (const float*)d_in[4];
    const float* br   = (const float*)d_in[5];
    const float* Wrel = (const float*)d_in[6];
    const float* brel = (const float*)d_in[7];
    float* out = (float*)d_out;

    float* ws = (float*)d_ws;
    float* LT    = ws;
    float* RT    = LT + (size_t)BB * DD * SS;
    float* sumLp = RT + (size_t)BB * DD * SS;
    float* sumRp = sumLp + BB * 2 * DD;
    float* absP  = sumRp + BB * 2 * DD;

    k_proj<<<256, 256, 0, stream>>>(X, emb, Wl, bl, Wr, br,
                                    LT, RT, sumLp, sumRp);
    k_pairs<<<512, 256, 0, stream>>>(LT, RT, absP);
    k_final<<<BB, 256, 0, stream>>>(sumLp, sumRp, absP, Wrel, brel, out);
}

// Round 5
// 29.630 us; speedup vs baseline: 1.8939x; 1.1641x over previous
//
#include <hip/hip_runtime.h>
#include <hip/hip_bf16.h>

#define DD 256
#define SS 128
#define BB 16

typedef __attribute__((ext_vector_type(8))) short bf16x8;
typedef __attribute__((ext_vector_type(4))) short bf16x4;
typedef __attribute__((ext_vector_type(4))) float f32x4;

static __device__ __forceinline__ short f2bf(float f) {
    __hip_bfloat16 h = __float2bfloat16(f);
    return *reinterpret_cast<short*>(&h);
}

// swizzled byte offset within a [rows][256 bf16 = 512B] LDS tile
static __device__ __forceinline__ int swz_off(int r, int kb) {
    return r * 512 + (kb ^ ((r & 7) << 4) ^ (((r >> 3) & 3) << 7));
}

// ws layout (floats):
//  Lsd  [B][S][D]    524288   (natural [token][d] layout)
//  Rsd  [B][S][D]    524288
//  sumLp[B][2][D]      8192
//  sumRp[B][2][D]      8192
//  absP [B][4][4][64] 16384

// ---------------- projection via bf16 MFMA ----------------
// grid 512 = 32 token-chunks(64 tok) x 16 col-chunks(32 of L|R); 256 thr = 4 waves.
__global__ __launch_bounds__(256) void k_proj(
    const int* __restrict__ X, const float* __restrict__ emb,
    const float* __restrict__ Wl, const float* __restrict__ bl,
    const float* __restrict__ Wr, const float* __restrict__ br,
    float* __restrict__ Lsd, float* __restrict__ Rsd,
    float* __restrict__ sumLp, float* __restrict__ sumRp)
{
    __shared__ __align__(16) short Ebf[64 * 256];   // 32 KB
    __shared__ __align__(16) short Wbf[32 * 256];   // 16 KB
    __shared__ float redw[4 * 16];
    __shared__ int toks[64];

    const int tid = threadIdx.x;
    const int bx  = blockIdx.x;
    const int tc  = bx >> 4;      // 0..31 : 64-token chunk
    const int cc  = bx & 15;      // 0..15 : 32-col chunk (0-7 -> L, 8-15 -> R)
    const int b   = tc >> 1;
    const int s0  = (tc & 1) * 64;
    const float* Wsrc = (cc < 8) ? Wl : Wr;
    const float* bsrc = (cc < 8) ? bl : br;
    const int dr0 = (cc & 7) * 32;

    if (tid < 64) toks[tid] = X[b * SS + s0 + tid];
    __syncthreads();

    char* Eb = (char*)Ebf;
    char* Wb = (char*)Wbf;

    // E staging: each wave-inst covers one full 1KB emb row (coalesced gather)
#pragma unroll
    for (int i = 0; i < 16; ++i) {
        int v = i * 256 + tid;
        int row = v >> 6, c4 = v & 63;
        float4 f = *(const float4*)&emb[(size_t)toks[row] * DD + c4 * 4];
        bf16x4 p; p[0] = f2bf(f.x); p[1] = f2bf(f.y); p[2] = f2bf(f.z); p[3] = f2bf(f.w);
        *(bf16x4*)(Eb + swz_off(row, c4 * 8)) = p;
    }
    // W staging: coalesced, one 1KB row per wave-inst
#pragma unroll
    for (int i = 0; i < 8; ++i) {
        int v = i * 256 + tid;
        int row = v >> 6, c4 = v & 63;
        float4 f = *(const float4*)&Wsrc[(size_t)(dr0 + row) * DD + c4 * 4];
        bf16x4 p; p[0] = f2bf(f.x); p[1] = f2bf(f.y); p[2] = f2bf(f.z); p[3] = f2bf(f.w);
        *(bf16x4*)(Wb + swz_off(row, c4 * 8)) = p;
    }
    __syncthreads();

    const int w    = tid >> 6;
    const int lane = tid & 63;
    const int wm = w >> 1, wn = w & 1;   // wave: 32-token half x 16-col half
    const int lr = lane & 15, lk = lane >> 4;

    f32x4 acc0 = {0.f, 0.f, 0.f, 0.f}, acc1 = acc0;
#pragma unroll
    for (int ks = 0; ks < 8; ++ks) {
        const int kb = ks * 64 + lk * 16;
        bf16x8 a0 = *(bf16x8*)(Eb + swz_off(wm * 32 + lr,      kb));
        bf16x8 a1 = *(bf16x8*)(Eb + swz_off(wm * 32 + 16 + lr, kb));
        bf16x8 b0 = *(bf16x8*)(Wb + swz_off(wn * 16 + lr,      kb));
        acc0 = __builtin_amdgcn_mfma_f32_16x16x32_bf16(a0, b0, acc0, 0, 0, 0);
        acc1 = __builtin_amdgcn_mfma_f32_16x16x32_bf16(a1, b0, acc1, 0, 0, 0);
    }

    // bias + DIRECT store to [b][s][d] (semi-coalesced: 4 rows x 64B per inst)
    const float bv = bsrc[dr0 + wn * 16 + lr];
    float* Tb = (cc < 8) ? Lsd : Rsd;
    const int dcol = dr0 + wn * 16 + lr;
#pragma unroll
    for (int reg = 0; reg < 4; ++reg) {
        int st = s0 + wm * 32 + lk * 4 + reg;
        Tb[((size_t)(b * SS) + st)      * DD + dcol] = acc0[reg] + bv;
        Tb[((size_t)(b * SS) + st + 16) * DD + dcol] = acc1[reg] + bv;
    }

    // token sums via cross-lane reduce (separable mean term)
    float t8 = (acc0[0] + acc0[1] + acc0[2] + acc0[3]) + bv * 8.0f
             + (acc1[0] + acc1[1] + acc1[2] + acc1[3]);
    t8 += __shfl_xor(t8, 16);
    t8 += __shfl_xor(t8, 32);
    if (lane < 16) redw[w * 16 + lr] = t8;
    __syncthreads();
    if (tid < 32) {
        int wn2 = tid >> 4, c = tid & 15;
        float s = redw[(0 * 2 + wn2) * 16 + c] + redw[(1 * 2 + wn2) * 16 + c];
        float* sp = (cc < 8) ? sumLp : sumRp;
        sp[(b * 2 + (tc & 1)) * DD + dr0 + wn2 * 16 + c] = s;
    }
}

// ---------------- all-pairs |L_i + R_j| partial sums ----------------
// grid 256 = b x 4 dchunk(64) x 4 isplit(32); 256 threads = 64 d x 4 j-groups
__global__ __launch_bounds__(256) void k_pairs(
    const float* __restrict__ Lsd, const float* __restrict__ Rsd,
    float* __restrict__ absP)
{
    __shared__ float Ll[64 * 33];     // [d][i32]
    __shared__ float Rl[64 * 129];    // [d][j128]
    __shared__ float red[256];
    const int tid = threadIdx.x;
    const int bx  = blockIdx.x;
    const int b   = bx >> 4;
    const int dc  = (bx >> 2) & 3;
    const int is  = bx & 3;

    // L: 32 s-rows x 64 d (coalesced 256B segments), transpose into Ll
#pragma unroll
    for (int it = 0; it < 2; ++it) {
        int v = it * 256 + tid;
        int srow = v >> 4, c4 = v & 15;
        float4 x = *(const float4*)&Lsd[((size_t)(b * SS) + is * 32 + srow) * DD + dc * 64 + c4 * 4];
        Ll[(c4 * 4 + 0) * 33 + srow] = x.x;
        Ll[(c4 * 4 + 1) * 33 + srow] = x.y;
        Ll[(c4 * 4 + 2) * 33 + srow] = x.z;
        Ll[(c4 * 4 + 3) * 33 + srow] = x.w;
    }
    // R: 128 s-rows x 64 d, transpose into Rl
#pragma unroll
    for (int it = 0; it < 8; ++it) {
        int v = it * 256 + tid;
        int j = v >> 4, c4 = v & 15;
        float4 x = *(const float4*)&Rsd[((size_t)(b * SS) + j) * DD + dc * 64 + c4 * 4];
        Rl[(c4 * 4 + 0) * 129 + j] = x.x;
        Rl[(c4 * 4 + 1) * 129 + j] = x.y;
        Rl[(c4 * 4 + 2) * 129 + j] = x.z;
        Rl[(c4 * 4 + 3) * 129 + j] = x.w;
    }
    __syncthreads();

    const int dl = tid & 63;
    const int jg = tid >> 6;
    float rr[32];
#pragma unroll
    for (int j = 0; j < 32; ++j) rr[j] = Rl[dl * 129 + jg * 32 + j];

    float a0 = 0.f, a1 = 0.f, a2 = 0.f, a3 = 0.f;
#pragma unroll
    for (int i = 0; i < 32; ++i) {
        float l = Ll[dl * 33 + i];
#pragma unroll
        for (int j = 0; j < 32; j += 4) {
            a0 += fabsf(l + rr[j + 0]);
            a1 += fabsf(l + rr[j + 1]);
            a2 += fabsf(l + rr[j + 2]);
            a3 += fabsf(l + rr[j + 3]);
        }
    }
    red[tid] = (a0 + a1) + (a2 + a3);
    __syncthreads();
    if (tid < 64) {
        float s = red[tid] + red[tid + 64] + red[tid + 128] + red[tid + 192];
        absP[((b * 4 + dc) * 4 + is) * 64 + tid] = s;
    }
}

// ---------------- final: pooled affine ----------------
__global__ __launch_bounds__(256) void k_final(
    const float* __restrict__ sumLp, const float* __restrict__ sumRp,
    const float* __restrict__ absP,
    const float* __restrict__ Wrel, const float* __restrict__ brel,
    float* __restrict__ out)
{
    __shared__ float plds[DD];
    const int tid = threadIdx.x;
    const int b   = blockIdx.x;

    float sl = sumLp[(b * 2 + 0) * DD + tid] + sumLp[(b * 2 + 1) * DD + tid];
    float sr = sumRp[(b * 2 + 0) * DD + tid] + sumRp[(b * 2 + 1) * DD + tid];

    const int dc = tid >> 6, dl = tid & 63;
    float sa = 0.f;
#pragma unroll
    for (int is = 0; is < 4; ++is)
        sa += absP[((b * 4 + dc) * 4 + is) * 64 + dl];

    // pooled = (S*(sumL+sumR) + sumAbs) / (2*S*S)
    plds[tid] = (128.0f * (sl + sr) + sa) * (1.0f / 32768.0f);
    __syncthreads();

    float acc = brel[tid];
    const float4* w4 = (const float4*)(Wrel + (size_t)tid * DD);
#pragma unroll
    for (int k4 = 0; k4 < DD / 4; ++k4) {
        float4 p = *(float4*)&plds[k4 * 4];
        float4 w = w4[k4];
        acc = fmaf(p.x, w.x, acc);
        acc = fmaf(p.y, w.y, acc);
        acc = fmaf(p.z, w.z, acc);
        acc = fmaf(p.w, w.w, acc);
    }
    out[b * DD + tid] = acc;
}

extern "C" void kernel_launch(void* const* d_in, const int* in_sizes, int n_in,
                              void* d_out, int out_size, void* d_ws, size_t ws_size,
                              hipStream_t stream) {
    const int*   X    = (const int*)d_in[0];
    const float* emb  = (const float*)d_in[1];
    const float* Wl   = (const float*)d_in[2];
    const float* bl   = (const float*)d_in[3];
    const float* Wr   = (const float*)d_in[4];
    const float* br   = (const float*)d_in[5];
    const float* Wrel = (const float*)d_in[6];
    const float* brel = (const float*)d_in[7];
    float* out = (float*)d_out;

    float* ws = (float*)d_ws;
    float* Lsd   = ws;
    float* Rsd   = Lsd + (size_t)BB * SS * DD;
    float* sumLp = Rsd + (size_t)BB * SS * DD;
    float* sumRp = sumLp + BB * 2 * DD;
    float* absP  = sumRp + BB * 2 * DD;

    k_proj<<<512, 256, 0, stream>>>(X, emb, Wl, bl, Wr, br,
                                    Lsd, Rsd, sumLp, sumRp);
    k_pairs<<<256, 256, 0, stream>>>(Lsd, Rsd, absP);
    k_final<<<BB, 256, 0, stream>>>(sumLp, sumRp, absP, Wrel, brel, out);
}